// Round 9
// baseline (742.094 us; speedup 1.0000x reference)
//
#include <hip/hip_runtime.h>
#include <hip/hip_bf16.h>

#define D 64
#define BIN_CAP 5120   // mean edges/bin = 4092 (E=1.6M, 391 bins), +16 sigma slack

// ---------------- K1: bin edges by dst>>8 (append-only writes) ----------------
// pairs entry = (dst&255)<<18 | src   (src < 2^18; nN = 100000)
__global__ void k_bin(const int* __restrict__ src, const int* __restrict__ dst,
                      int* __restrict__ cursor, int* __restrict__ pairs, int nE) {
    int e = blockIdx.x * 256 + threadIdx.x;
    if (e >= nE) return;
    int d = __builtin_nontemporal_load(&dst[e]);
    int s = __builtin_nontemporal_load(&src[e]);
    int rb = d >> 8;
    int pos = atomicAdd(&cursor[rb], 1);
    if (pos < BIN_CAP) pairs[(size_t)rb * BIN_CAP + pos] = ((d & 255) << 18) | s;
}

// ---------------- K2: per-bin LDS counting sort -> dense CSR segment ----------
// One block per bin. All global writes are block-private contiguous regions:
// zero cross-block line sharing -> no write amplification by construction.
__global__ __launch_bounds__(256) void k_csr(
        const int* __restrict__ cursor, const int* __restrict__ pairs,
        int* __restrict__ csr, int* __restrict__ row_start, int* __restrict__ deg,
        int nN) {
    __shared__ int cnt[256];
    __shared__ int wsum[4];
    const int r = blockIdx.x;
    const int t = threadIdx.x;
    const int lane = t & 63, wv = t >> 6;
    const int nr = min(cursor[r], BIN_CAP);
    const int* bp = &pairs[(size_t)r * BIN_CAP];

    cnt[t] = 0;
    __syncthreads();
    for (int i = t; i < nr; i += 256) atomicAdd(&cnt[bp[i] >> 18], 1);
    __syncthreads();

    const int myc = cnt[t];
    const int node = r * 256 + t;
    if (node < nN) deg[node] = myc;

    // exclusive scan over 256 counts (shfl wave-scan + cross-wave fixup)
    int incl = myc;
    for (int off = 1; off < 64; off <<= 1) {
        int u = __shfl_up(incl, off, 64);
        if (lane >= off) incl += u;
    }
    if (lane == 63) wsum[wv] = incl;
    __syncthreads();
    if (t == 0) {
        int run = 0;
        for (int i = 0; i < 4; ++i) { int v = wsum[i]; wsum[i] = run; run += v; }
    }
    __syncthreads();
    const int excl = wsum[wv] + incl - myc;
    if (node < nN) row_start[node] = r * BIN_CAP + excl;

    __syncthreads();
    cnt[t] = excl;          // repurpose as placement cursor
    __syncthreads();
    for (int i = t; i < nr; i += 256) {
        int p = bp[i];
        int pos = atomicAdd(&cnt[p >> 18], 1);
        csr[(size_t)r * BIN_CAP + pos] = p & 0x3FFFF;
    }
}

// ---------------- K3: dense pre-GEMM ----------------
// ylb = x @ W_l (bf16 table; mean commutes with the linear map).
// out = x @ W_r + b (f32, no relu) — gather adds the mean term on top.
__global__ __launch_bounds__(256) void k_pre(
        const float* __restrict__ x, const float* __restrict__ Wl,
        const float* __restrict__ Wr, const float* __restrict__ b,
        unsigned short* __restrict__ ylb, float* __restrict__ out, int nN) {
    __shared__ float sX[64 * 65];    // stride 65 -> <=2-way bank alias (free)
    __shared__ float swl[64 * 64];
    __shared__ float swr[64 * 64];
    __shared__ float sB[64];

    const int t = threadIdx.x;
    for (int i = t; i < 4096; i += 256) { swl[i] = Wl[i]; swr[i] = Wr[i]; }
    if (t < 64) sB[t] = b[t];

    const int lane = t & 63, wv = t >> 6;
    const int tile = blockIdx.x * 64;
    for (int q = 0; q < 16; ++q) {
        int nd = wv * 16 + q, g = tile + nd;
        sX[nd * 65 + lane] = (g < nN) ? __builtin_nontemporal_load(&x[(size_t)g * D + lane]) : 0.f;
    }
    __syncthreads();

    const int n0 = (t & 15) * 4;
    const int c0 = (t >> 4) * 4;
    float accl[4][4] = {}, accr[4][4] = {};
#pragma unroll 4
    for (int k = 0; k < D; ++k) {
        float a0 = sX[(n0 + 0) * 65 + k], a1 = sX[(n0 + 1) * 65 + k];
        float a2 = sX[(n0 + 2) * 65 + k], a3 = sX[(n0 + 3) * 65 + k];
        float4 wl4 = *(const float4*)&swl[k * D + c0];
        float4 wr4 = *(const float4*)&swr[k * D + c0];
        accl[0][0] += a0 * wl4.x; accl[0][1] += a0 * wl4.y; accl[0][2] += a0 * wl4.z; accl[0][3] += a0 * wl4.w;
        accl[1][0] += a1 * wl4.x; accl[1][1] += a1 * wl4.y; accl[1][2] += a1 * wl4.z; accl[1][3] += a1 * wl4.w;
        accl[2][0] += a2 * wl4.x; accl[2][1] += a2 * wl4.y; accl[2][2] += a2 * wl4.z; accl[2][3] += a2 * wl4.w;
        accl[3][0] += a3 * wl4.x; accl[3][1] += a3 * wl4.y; accl[3][2] += a3 * wl4.z; accl[3][3] += a3 * wl4.w;
        accr[0][0] += a0 * wr4.x; accr[0][1] += a0 * wr4.y; accr[0][2] += a0 * wr4.z; accr[0][3] += a0 * wr4.w;
        accr[1][0] += a1 * wr4.x; accr[1][1] += a1 * wr4.y; accr[1][2] += a1 * wr4.z; accr[1][3] += a1 * wr4.w;
        accr[2][0] += a2 * wr4.x; accr[2][1] += a2 * wr4.y; accr[2][2] += a2 * wr4.z; accr[2][3] += a2 * wr4.w;
        accr[3][0] += a3 * wr4.x; accr[3][1] += a3 * wr4.y; accr[3][2] += a3 * wr4.z; accr[3][3] += a3 * wr4.w;
    }

#pragma unroll
    for (int i = 0; i < 4; ++i) {
        int g = tile + n0 + i;
        if (g >= nN) continue;
        __hip_bfloat162 l01 = __float22bfloat162_rn(make_float2(accl[i][0], accl[i][1]));
        __hip_bfloat162 l23 = __float22bfloat162_rn(make_float2(accl[i][2], accl[i][3]));
        uint2 pl = make_uint2(*(unsigned int*)&l01, *(unsigned int*)&l23);
        *(uint2*)&ylb[(size_t)g * D + c0] = pl;
        float4 o;
        o.x = accr[i][0] + sB[c0 + 0];
        o.y = accr[i][1] + sB[c0 + 1];
        o.z = accr[i][2] + sB[c0 + 2];
        o.w = accr[i][3] + sB[c0 + 3];
        *(float4*)&out[(size_t)g * D + c0] = o;   // self term, f32, no relu yet
    }
}

// ---------------- K4: gather-mean + finalize ----------------
// Half-wave per node; node's csr entries are contiguous -> one coalesced load
// covers 32 edges; shfl-broadcast. Plain loads (nt regressed in R8).
__device__ __forceinline__ float bl(unsigned p) { return __uint_as_float(p << 16); }
__device__ __forceinline__ float bh(unsigned p) { return __uint_as_float(p & 0xffff0000u); }

__global__ __launch_bounds__(256) void k_gather(
        const unsigned int* __restrict__ ylb, const int* __restrict__ row_start,
        const int* __restrict__ deg, const int* __restrict__ csr,
        float* __restrict__ out, int nN) {
    const int t = threadIdx.x;
    const int lane32 = t & 31;
    const int node = blockIdx.x * 8 + (t >> 5);
    if (node >= nN) return;

    const int dg = deg[node];
    const int n = min(dg, 64);            // P(deg>64) ~ 1e-18 at mean 16
    const int rs = row_start[node];

    int idxA = (lane32 < n) ? csr[rs + lane32] : 0;
    int idxB = (32 + lane32 < n) ? csr[rs + 32 + lane32] : 0;

    float s0 = 0.f, s1 = 0.f, t0 = 0.f, t1 = 0.f;
    float u0 = 0.f, u1 = 0.f, v0 = 0.f, v1 = 0.f;

    const int n1 = min(n, 32);
    int k = 0;
    for (; k + 4 <= n1; k += 4) {
        int i0 = __shfl(idxA, k, 32), i1 = __shfl(idxA, k + 1, 32);
        int i2 = __shfl(idxA, k + 2, 32), i3 = __shfl(idxA, k + 3, 32);
        unsigned p0 = ylb[(size_t)i0 * 32 + lane32];
        unsigned p1 = ylb[(size_t)i1 * 32 + lane32];
        unsigned p2 = ylb[(size_t)i2 * 32 + lane32];
        unsigned p3 = ylb[(size_t)i3 * 32 + lane32];
        s0 += bl(p0); s1 += bh(p0);
        t0 += bl(p1); t1 += bh(p1);
        u0 += bl(p2); u1 += bh(p2);
        v0 += bl(p3); v1 += bh(p3);
    }
    for (; k < n1; ++k) {
        int i0 = __shfl(idxA, k, 32);
        unsigned p0 = ylb[(size_t)i0 * 32 + lane32];
        s0 += bl(p0); s1 += bh(p0);
    }
    const int n2 = n - 32;
    k = 0;
    for (; k + 4 <= n2; k += 4) {
        int i0 = __shfl(idxB, k, 32), i1 = __shfl(idxB, k + 1, 32);
        int i2 = __shfl(idxB, k + 2, 32), i3 = __shfl(idxB, k + 3, 32);
        unsigned p0 = ylb[(size_t)i0 * 32 + lane32];
        unsigned p1 = ylb[(size_t)i1 * 32 + lane32];
        unsigned p2 = ylb[(size_t)i2 * 32 + lane32];
        unsigned p3 = ylb[(size_t)i3 * 32 + lane32];
        s0 += bl(p0); s1 += bh(p0);
        t0 += bl(p1); t1 += bh(p1);
        u0 += bl(p2); u1 += bh(p2);
        v0 += bl(p3); v1 += bh(p3);
    }
    for (; k < n2; ++k) {
        int i0 = __shfl(idxB, k, 32);
        unsigned p0 = ylb[(size_t)i0 * 32 + lane32];
        s0 += bl(p0); s1 += bh(p0);
    }

    const float inv = 1.f / fmaxf((float)dg, 1.f);
    const float m0 = ((s0 + t0) + (u0 + v0)) * inv;
    const float m1 = ((s1 + t1) + (u1 + v1)) * inv;

    float2* po = (float2*)&out[(size_t)node * D + lane32 * 2];
    float2 r = *po;                      // self term written by k_pre
    r.x = fmaxf(m0 + r.x, 0.f);
    r.y = fmaxf(m1 + r.y, 0.f);
    *po = r;
}

extern "C" void kernel_launch(void* const* d_in, const int* in_sizes, int n_in,
                              void* d_out, int out_size, void* d_ws, size_t ws_size,
                              hipStream_t stream) {
    const float* x  = (const float*)d_in[0];
    const int*   ei = (const int*)d_in[1];      // [2, E]: row 0 = src, row 1 = dst
    const float* Wl = (const float*)d_in[2];
    const float* Wr = (const float*)d_in[3];
    const float* b  = (const float*)d_in[4];
    float*       out = (float*)d_out;

    const int nN = in_sizes[0] / D;   // 100000
    const int nE = in_sizes[1] / 2;   // 1600000
    const int* src = ei;
    const int* dst = ei + nE;

    const int nbins = (nN + 255) >> 8;   // 391

    // workspace layout (~29.6 MB)
    int* cursor    = (int*)d_ws;                        // [512]
    int* pairs     = cursor + 512;                      // [nbins*BIN_CAP]  8 MB
    int* csr       = pairs + (size_t)nbins * BIN_CAP;   // [nbins*BIN_CAP]  8 MB
    int* row_start = csr + (size_t)nbins * BIN_CAP;     // [nN]
    int* deg       = row_start + nN;                    // [nN]
    unsigned short* ylb = (unsigned short*)(deg + nN);  // [nN*64] bf16

    hipMemsetAsync(cursor, 0, 512 * sizeof(int), stream);

    k_bin   <<<(nE + 255) / 256, 256, 0, stream>>>(src, dst, cursor, pairs, nE);
    k_csr   <<<nbins, 256, 0, stream>>>(cursor, pairs, csr, row_start, deg, nN);
    k_pre   <<<(nN + 63) / 64, 256, 0, stream>>>(x, Wl, Wr, b, ylb, out, nN);
    k_gather<<<(nN + 7) / 8, 256, 0, stream>>>((const unsigned int*)ylb, row_start, deg, csr, out, nN);
}

// Round 10
// 480.679 us; speedup vs baseline: 1.5438x; 1.5438x over previous
//
#include <hip/hip_runtime.h>
#include <hip/hip_bf16.h>

#define D 64
#define BIN_CAP 5120     // mean edges/bin = 4096, +16 sigma slack
#define NBINS_MAX 400    // nbins = ceil(nN/256) = 391
#define CUR_STRIDE 16    // pad cursors to one 64B line each (kills false sharing)

// ---------------- K1: LDS-ring-staged binning ----------------
// Per-block LDS ring per bin; flush in 32-entry (128B) line-aligned granules.
// Global cursor advances only in multiples of 32 -> every 64B line of pairs is
// written entirely by ONE block (write-once, no cross-XCD line sharing).
// Global atomics: 1.6M -> ~50K, on padded (1/line) cursors.
__global__ __launch_bounds__(256) void k_bin(
        const int* __restrict__ src, const int* __restrict__ dst,
        int* __restrict__ gcur, int* __restrict__ pairs, int nE, int nbins) {
    __shared__ int tail[NBINS_MAX], head[NBINS_MAX];
    __shared__ int buf[NBINS_MAX * 64];          // ring, 64 entries/bin
    __shared__ int flist[NBINS_MAX], fcnt[NBINS_MAX], fpos[NBINS_MAX], fhead[NBINS_MAX];
    __shared__ int nflush;
    const int t = threadIdx.x;
    for (int i = t; i < nbins; i += 256) { tail[i] = 0; head[i] = 0; }
    if (t == 0) nflush = 0;
    __syncthreads();

    const int per = (nE + gridDim.x - 1) / gridDim.x;
    const int e0 = blockIdx.x * per;
    const int e1 = min(e0 + per, nE);

    for (int base = e0; base < e1; base += 256) {
        int e = base + t;
        if (e < e1) {
            int d = dst[e], s = src[e];
            int b = d >> 8;
            int pos = atomicAdd(&tail[b], 1);          // LDS atomic
            buf[(b << 6) + (pos & 63)] = ((d & 255) << 18) | s;
        }
        __syncthreads();
        // flush-scan: bins that crossed a 32-entry granule
        for (int b = t; b < nbins; b += 256) {
            int nf = (tail[b] - head[b]) & ~31;
            if (nf > 0) {
                int fi = atomicAdd(&nflush, 1);
                flist[fi] = b; fcnt[fi] = nf; fhead[fi] = head[b];
                fpos[fi] = atomicAdd(&gcur[b * CUR_STRIDE], nf);
                head[b] += nf;
            }
        }
        __syncthreads();
        // cooperative copy: full-line contiguous writes
        int nfl = nflush;
        for (int f = 0; f < nfl; ++f) {
            int b = flist[f], n = fcnt[f], hp = fhead[f], gp = fpos[f];
            for (int i = t; i < n; i += 256) {
                int p = gp + i;
                if (p < BIN_CAP) pairs[(size_t)b * BIN_CAP + p] = buf[(b << 6) + ((hp + i) & 63)];
            }
        }
        __syncthreads();
        if (t == 0) nflush = 0;   // next read of nflush is after the next barrier
    }
    // drain residuals (<32 per bin; the only partial-line writes)
    __syncthreads();
    for (int b = t; b < nbins; b += 256) {
        int pend = tail[b] - head[b];
        if (pend > 0) {
            int fi = atomicAdd(&nflush, 1);
            flist[fi] = b; fcnt[fi] = pend; fhead[fi] = head[b];
            fpos[fi] = atomicAdd(&gcur[b * CUR_STRIDE], pend);
        }
    }
    __syncthreads();
    int nfl = nflush;
    for (int f = 0; f < nfl; ++f) {
        int b = flist[f], n = fcnt[f], hp = fhead[f], gp = fpos[f];
        for (int i = t; i < n; i += 256) {
            int p = gp + i;
            if (p < BIN_CAP) pairs[(size_t)b * BIN_CAP + p] = buf[(b << 6) + ((hp + i) & 63)];
        }
    }
}

// ---------------- K2: per-bin LDS counting sort -> dense CSR segment ----------
__global__ __launch_bounds__(256) void k_csr(
        const int* __restrict__ gcur, const int* __restrict__ pairs,
        int* __restrict__ csr, int* __restrict__ row_start, int* __restrict__ deg,
        int nN) {
    __shared__ int cnt[256];
    __shared__ int wsum[4];
    const int r = blockIdx.x;
    const int t = threadIdx.x;
    const int lane = t & 63, wv = t >> 6;
    const int nr = min(gcur[r * CUR_STRIDE], BIN_CAP);
    const int* bp = &pairs[(size_t)r * BIN_CAP];

    cnt[t] = 0;
    __syncthreads();
    for (int i = t; i < nr; i += 256) atomicAdd(&cnt[bp[i] >> 18], 1);
    __syncthreads();

    const int myc = cnt[t];
    const int node = r * 256 + t;
    if (node < nN) deg[node] = myc;

    int incl = myc;
    for (int off = 1; off < 64; off <<= 1) {
        int u = __shfl_up(incl, off, 64);
        if (lane >= off) incl += u;
    }
    if (lane == 63) wsum[wv] = incl;
    __syncthreads();
    if (t == 0) {
        int run = 0;
        for (int i = 0; i < 4; ++i) { int v = wsum[i]; wsum[i] = run; run += v; }
    }
    __syncthreads();
    const int excl = wsum[wv] + incl - myc;
    if (node < nN) row_start[node] = r * BIN_CAP + excl;

    __syncthreads();
    cnt[t] = excl;          // repurpose as placement cursor
    __syncthreads();
    for (int i = t; i < nr; i += 256) {
        int p = bp[i];
        int pos = atomicAdd(&cnt[p >> 18], 1);
        csr[(size_t)r * BIN_CAP + pos] = p & 0x3FFFF;
    }
}

// ---------------- K3: dense pre-GEMM ----------------
// ylb = x @ W_l (bf16 table; mean commutes with the linear map).
// out = x @ W_r + b (f32, no relu) — gather adds the mean term on top.
__global__ __launch_bounds__(256) void k_pre(
        const float* __restrict__ x, const float* __restrict__ Wl,
        const float* __restrict__ Wr, const float* __restrict__ b,
        unsigned short* __restrict__ ylb, float* __restrict__ out, int nN) {
    __shared__ float sX[64 * 65];    // stride 65 -> <=2-way bank alias (free)
    __shared__ float swl[64 * 64];
    __shared__ float swr[64 * 64];
    __shared__ float sB[64];

    const int t = threadIdx.x;
    for (int i = t; i < 4096; i += 256) { swl[i] = Wl[i]; swr[i] = Wr[i]; }
    if (t < 64) sB[t] = b[t];

    const int lane = t & 63, wv = t >> 6;
    const int tile = blockIdx.x * 64;
    for (int q = 0; q < 16; ++q) {
        int nd = wv * 16 + q, g = tile + nd;
        sX[nd * 65 + lane] = (g < nN) ? x[(size_t)g * D + lane] : 0.f;
    }
    __syncthreads();

    const int n0 = (t & 15) * 4;
    const int c0 = (t >> 4) * 4;
    float accl[4][4] = {}, accr[4][4] = {};
#pragma unroll 4
    for (int k = 0; k < D; ++k) {
        float a0 = sX[(n0 + 0) * 65 + k], a1 = sX[(n0 + 1) * 65 + k];
        float a2 = sX[(n0 + 2) * 65 + k], a3 = sX[(n0 + 3) * 65 + k];
        float4 wl4 = *(const float4*)&swl[k * D + c0];
        float4 wr4 = *(const float4*)&swr[k * D + c0];
        accl[0][0] += a0 * wl4.x; accl[0][1] += a0 * wl4.y; accl[0][2] += a0 * wl4.z; accl[0][3] += a0 * wl4.w;
        accl[1][0] += a1 * wl4.x; accl[1][1] += a1 * wl4.y; accl[1][2] += a1 * wl4.z; accl[1][3] += a1 * wl4.w;
        accl[2][0] += a2 * wl4.x; accl[2][1] += a2 * wl4.y; accl[2][2] += a2 * wl4.z; accl[2][3] += a2 * wl4.w;
        accl[3][0] += a3 * wl4.x; accl[3][1] += a3 * wl4.y; accl[3][2] += a3 * wl4.z; accl[3][3] += a3 * wl4.w;
        accr[0][0] += a0 * wr4.x; accr[0][1] += a0 * wr4.y; accr[0][2] += a0 * wr4.z; accr[0][3] += a0 * wr4.w;
        accr[1][0] += a1 * wr4.x; accr[1][1] += a1 * wr4.y; accr[1][2] += a1 * wr4.z; accr[1][3] += a1 * wr4.w;
        accr[2][0] += a2 * wr4.x; accr[2][1] += a2 * wr4.y; accr[2][2] += a2 * wr4.z; accr[2][3] += a2 * wr4.w;
        accr[3][0] += a3 * wr4.x; accr[3][1] += a3 * wr4.y; accr[3][2] += a3 * wr4.z; accr[3][3] += a3 * wr4.w;
    }

#pragma unroll
    for (int i = 0; i < 4; ++i) {
        int g = tile + n0 + i;
        if (g >= nN) continue;
        __hip_bfloat162 l01 = __float22bfloat162_rn(make_float2(accl[i][0], accl[i][1]));
        __hip_bfloat162 l23 = __float22bfloat162_rn(make_float2(accl[i][2], accl[i][3]));
        uint2 pl = make_uint2(*(unsigned int*)&l01, *(unsigned int*)&l23);
        *(uint2*)&ylb[(size_t)g * D + c0] = pl;
        float4 o;
        o.x = accr[i][0] + sB[c0 + 0];
        o.y = accr[i][1] + sB[c0 + 1];
        o.z = accr[i][2] + sB[c0 + 2];
        o.w = accr[i][3] + sB[c0 + 3];
        *(float4*)&out[(size_t)g * D + c0] = o;   // self term, f32, no relu yet
    }
}

// ---------------- K4: gather-mean + finalize ----------------
__device__ __forceinline__ float bl(unsigned p) { return __uint_as_float(p << 16); }
__device__ __forceinline__ float bh(unsigned p) { return __uint_as_float(p & 0xffff0000u); }

__global__ __launch_bounds__(256) void k_gather(
        const unsigned int* __restrict__ ylb, const int* __restrict__ row_start,
        const int* __restrict__ deg, const int* __restrict__ csr,
        float* __restrict__ out, int nN) {
    const int t = threadIdx.x;
    const int lane32 = t & 31;
    const int node = blockIdx.x * 8 + (t >> 5);
    if (node >= nN) return;

    const int dg = deg[node];
    const int n = min(dg, 64);            // P(deg>64) ~ 1e-18 at mean 16
    const int rs = row_start[node];

    int idxA = (lane32 < n) ? csr[rs + lane32] : 0;
    int idxB = (32 + lane32 < n) ? csr[rs + 32 + lane32] : 0;

    float s0 = 0.f, s1 = 0.f, t0 = 0.f, t1 = 0.f;
    float u0 = 0.f, u1 = 0.f, v0 = 0.f, v1 = 0.f;

    const int n1 = min(n, 32);
    int k = 0;
    for (; k + 4 <= n1; k += 4) {
        int i0 = __shfl(idxA, k, 32), i1 = __shfl(idxA, k + 1, 32);
        int i2 = __shfl(idxA, k + 2, 32), i3 = __shfl(idxA, k + 3, 32);
        unsigned p0 = ylb[(size_t)i0 * 32 + lane32];
        unsigned p1 = ylb[(size_t)i1 * 32 + lane32];
        unsigned p2 = ylb[(size_t)i2 * 32 + lane32];
        unsigned p3 = ylb[(size_t)i3 * 32 + lane32];
        s0 += bl(p0); s1 += bh(p0);
        t0 += bl(p1); t1 += bh(p1);
        u0 += bl(p2); u1 += bh(p2);
        v0 += bl(p3); v1 += bh(p3);
    }
    for (; k < n1; ++k) {
        int i0 = __shfl(idxA, k, 32);
        unsigned p0 = ylb[(size_t)i0 * 32 + lane32];
        s0 += bl(p0); s1 += bh(p0);
    }
    const int n2 = n - 32;
    k = 0;
    for (; k + 4 <= n2; k += 4) {
        int i0 = __shfl(idxB, k, 32), i1 = __shfl(idxB, k + 1, 32);
        int i2 = __shfl(idxB, k + 2, 32), i3 = __shfl(idxB, k + 3, 32);
        unsigned p0 = ylb[(size_t)i0 * 32 + lane32];
        unsigned p1 = ylb[(size_t)i1 * 32 + lane32];
        unsigned p2 = ylb[(size_t)i2 * 32 + lane32];
        unsigned p3 = ylb[(size_t)i3 * 32 + lane32];
        s0 += bl(p0); s1 += bh(p0);
        t0 += bl(p1); t1 += bh(p1);
        u0 += bl(p2); u1 += bh(p2);
        v0 += bl(p3); v1 += bh(p3);
    }
    for (; k < n2; ++k) {
        int i0 = __shfl(idxB, k, 32);
        unsigned p0 = ylb[(size_t)i0 * 32 + lane32];
        s0 += bl(p0); s1 += bh(p0);
    }

    const float inv = 1.f / fmaxf((float)dg, 1.f);
    const float m0 = ((s0 + t0) + (u0 + v0)) * inv;
    const float m1 = ((s1 + t1) + (u1 + v1)) * inv;

    float2* po = (float2*)&out[(size_t)node * D + lane32 * 2];
    float2 r = *po;                      // self term written by k_pre
    r.x = fmaxf(m0 + r.x, 0.f);
    r.y = fmaxf(m1 + r.y, 0.f);
    *po = r;
}

extern "C" void kernel_launch(void* const* d_in, const int* in_sizes, int n_in,
                              void* d_out, int out_size, void* d_ws, size_t ws_size,
                              hipStream_t stream) {
    const float* x  = (const float*)d_in[0];
    const int*   ei = (const int*)d_in[1];      // [2, E]: row 0 = src, row 1 = dst
    const float* Wl = (const float*)d_in[2];
    const float* Wr = (const float*)d_in[3];
    const float* b  = (const float*)d_in[4];
    float*       out = (float*)d_out;

    const int nN = in_sizes[0] / D;   // 100000
    const int nE = in_sizes[1] / 2;   // 1600000
    const int* src = ei;
    const int* dst = ei + nE;

    const int nbins = (nN + 255) >> 8;   // 391

    // workspace layout (~29.6 MB)
    int* gcur      = (int*)d_ws;                          // [nbins*CUR_STRIDE] padded cursors
    int* pairs     = gcur + (size_t)NBINS_MAX * CUR_STRIDE; // [nbins*BIN_CAP]  8 MB
    int* csr       = pairs + (size_t)nbins * BIN_CAP;     // [nbins*BIN_CAP]  8 MB
    int* row_start = csr + (size_t)nbins * BIN_CAP;       // [nN]
    int* deg       = row_start + nN;                      // [nN]
    unsigned short* ylb = (unsigned short*)(deg + nN);    // [nN*64] bf16

    hipMemsetAsync(gcur, 0, (size_t)NBINS_MAX * CUR_STRIDE * sizeof(int), stream);

    k_bin   <<<64, 256, 0, stream>>>(src, dst, gcur, pairs, nE, nbins);
    k_csr   <<<nbins, 256, 0, stream>>>(gcur, pairs, csr, row_start, deg, nN);
    k_pre   <<<(nN + 63) / 64, 256, 0, stream>>>(x, Wl, Wr, b, ylb, out, nN);
    k_gather<<<(nN + 7) / 8, 256, 0, stream>>>((const unsigned int*)ylb, row_start, deg, csr, out, nN);
}

// Round 11
// 230.747 us; speedup vs baseline: 3.2161x; 2.0831x over previous
//
#include <hip/hip_runtime.h>
#include <hip/hip_bf16.h>

#define D 64
#define BK_CHUNK 4096

// ---------------- K1: fused scatter + pre-GEMM ----------------
// Heterogeneous blocks, 2:1 interleave:
//   bid%3 != 2 -> scatter virtual block sid = 2*(bid/3) + bid%3  (R6-proven:
//                 8-range XCD partition, fixed-stride slots, plain loads)
//   bid%3 == 2 -> pre-GEMM tile g = bid/3: ylb = x@W_l (bf16), out = x@W_r + b (f32)
// Rationale: scatter is atomic/latency-bound (VALUBusy ~5%), pre is
// compute-bound; co-resident waves overlap (time ~ max, not sum).
// Pre reads weights straight from global (L1/L2-resident 32KB) so the fused
// LDS footprint stays at ~17KB and doesn't throttle scatter-block residency.
__global__ __launch_bounds__(256) void k_fused(
        const float* __restrict__ x, const int* __restrict__ src,
        const int* __restrict__ dst, const float* __restrict__ Wl,
        const float* __restrict__ Wr, const float* __restrict__ b,
        int* __restrict__ cnt, int* __restrict__ slots,
        unsigned short* __restrict__ ylb, float* __restrict__ out,
        int nE, int nN, int cap) {
    __shared__ float sX[64 * 65];   // stride 65: <=2-way bank alias (free)
    __shared__ float sB[64];

    const int bid = blockIdx.x;
    const int g = bid / 3, r = bid % 3;
    const int t = threadIdx.x;

    if (r != 2) {
        // ---- scatter path (exactly R6's k_scatter) ----
        const int sid   = 2 * g + r;
        const int rng   = sid & 7;
        const int chunk = sid >> 3;
        const int rsz = (nN + 7) / 8;
        const int lo = rng * rsz;
        const int hi = min(lo + rsz, nN);
        const int e0 = chunk * BK_CHUNK;
        const int e1 = min(e0 + BK_CHUNK, nE);
        for (int e = e0 + t; e < e1; e += 256) {
            int d = dst[e];
            if (d >= lo && d < hi) {
                int pos = atomicAdd(&cnt[d], 1);
                if (pos < cap) slots[(size_t)d * cap + pos] = src[e];
            }
        }
        return;
    }

    // ---- pre path: tile g (64 nodes) ----
    const int lane = t & 63, wv = t >> 6;
    const int tile = g * 64;
    if (t < 64) sB[t] = b[t];
    for (int q = 0; q < 16; ++q) {
        int nd = wv * 16 + q, gg = tile + nd;
        sX[nd * 65 + lane] = (gg < nN) ? x[(size_t)gg * D + lane] : 0.f;
    }
    __syncthreads();

    const int n0 = (t & 15) * 4;
    const int c0 = (t >> 4) * 4;
    float accl[4][4] = {}, accr[4][4] = {};
#pragma unroll 4
    for (int k = 0; k < D; ++k) {
        float a0 = sX[(n0 + 0) * 65 + k], a1 = sX[(n0 + 1) * 65 + k];
        float a2 = sX[(n0 + 2) * 65 + k], a3 = sX[(n0 + 3) * 65 + k];
        float4 wl4 = *(const float4*)&Wl[k * D + c0];   // 16-lane broadcast, L1-resident
        float4 wr4 = *(const float4*)&Wr[k * D + c0];
        accl[0][0] += a0 * wl4.x; accl[0][1] += a0 * wl4.y; accl[0][2] += a0 * wl4.z; accl[0][3] += a0 * wl4.w;
        accl[1][0] += a1 * wl4.x; accl[1][1] += a1 * wl4.y; accl[1][2] += a1 * wl4.z; accl[1][3] += a1 * wl4.w;
        accl[2][0] += a2 * wl4.x; accl[2][1] += a2 * wl4.y; accl[2][2] += a2 * wl4.z; accl[2][3] += a2 * wl4.w;
        accl[3][0] += a3 * wl4.x; accl[3][1] += a3 * wl4.y; accl[3][2] += a3 * wl4.z; accl[3][3] += a3 * wl4.w;
        accr[0][0] += a0 * wr4.x; accr[0][1] += a0 * wr4.y; accr[0][2] += a0 * wr4.z; accr[0][3] += a0 * wr4.w;
        accr[1][0] += a1 * wr4.x; accr[1][1] += a1 * wr4.y; accr[1][2] += a1 * wr4.z; accr[1][3] += a1 * wr4.w;
        accr[2][0] += a2 * wr4.x; accr[2][1] += a2 * wr4.y; accr[2][2] += a2 * wr4.z; accr[2][3] += a2 * wr4.w;
        accr[3][0] += a3 * wr4.x; accr[3][1] += a3 * wr4.y; accr[3][2] += a3 * wr4.z; accr[3][3] += a3 * wr4.w;
    }

#pragma unroll
    for (int i = 0; i < 4; ++i) {
        int gg = tile + n0 + i;
        if (gg >= nN) continue;
        __hip_bfloat162 l01 = __float22bfloat162_rn(make_float2(accl[i][0], accl[i][1]));
        __hip_bfloat162 l23 = __float22bfloat162_rn(make_float2(accl[i][2], accl[i][3]));
        uint2 pl = make_uint2(*(unsigned int*)&l01, *(unsigned int*)&l23);
        *(uint2*)&ylb[(size_t)gg * D + c0] = pl;
        float4 o;
        o.x = accr[i][0] + sB[c0 + 0];
        o.y = accr[i][1] + sB[c0 + 1];
        o.z = accr[i][2] + sB[c0 + 2];
        o.w = accr[i][3] + sB[c0 + 3];
        *(float4*)&out[(size_t)gg * D + c0] = o;   // self term, f32, no relu yet
    }
}

// ---------------- K2: gather-mean + finalize (R6-proven, plain loads) --------
__device__ __forceinline__ float bl(unsigned p) { return __uint_as_float(p << 16); }
__device__ __forceinline__ float bh(unsigned p) { return __uint_as_float(p & 0xffff0000u); }

__global__ __launch_bounds__(256) void k_gather(
        const unsigned int* __restrict__ ylb, const int* __restrict__ cnt,
        const int* __restrict__ slots, float* __restrict__ out, int nN, int cap) {
    const int t = threadIdx.x;
    const int lane32 = t & 31;
    const int node = blockIdx.x * 8 + (t >> 5);
    if (node >= nN) return;

    const int deg = cnt[node];
    const int n = min(deg, cap);
    const size_t base = (size_t)node * cap;

    int idxA = (lane32 < n) ? slots[base + lane32] : 0;
    int idxB = (32 + lane32 < n) ? slots[base + 32 + lane32] : 0;

    float s0 = 0.f, s1 = 0.f, t0 = 0.f, t1 = 0.f;
    float u0 = 0.f, u1 = 0.f, v0 = 0.f, v1 = 0.f;

    const int n1 = min(n, 32);
    int k = 0;
    for (; k + 4 <= n1; k += 4) {
        int i0 = __shfl(idxA, k, 32), i1 = __shfl(idxA, k + 1, 32);
        int i2 = __shfl(idxA, k + 2, 32), i3 = __shfl(idxA, k + 3, 32);
        unsigned p0 = ylb[(size_t)i0 * 32 + lane32];
        unsigned p1 = ylb[(size_t)i1 * 32 + lane32];
        unsigned p2 = ylb[(size_t)i2 * 32 + lane32];
        unsigned p3 = ylb[(size_t)i3 * 32 + lane32];
        s0 += bl(p0); s1 += bh(p0);
        t0 += bl(p1); t1 += bh(p1);
        u0 += bl(p2); u1 += bh(p2);
        v0 += bl(p3); v1 += bh(p3);
    }
    for (; k < n1; ++k) {
        int i0 = __shfl(idxA, k, 32);
        unsigned p0 = ylb[(size_t)i0 * 32 + lane32];
        s0 += bl(p0); s1 += bh(p0);
    }
    const int n2 = n - 32;
    k = 0;
    for (; k + 4 <= n2; k += 4) {
        int i0 = __shfl(idxB, k, 32), i1 = __shfl(idxB, k + 1, 32);
        int i2 = __shfl(idxB, k + 2, 32), i3 = __shfl(idxB, k + 3, 32);
        unsigned p0 = ylb[(size_t)i0 * 32 + lane32];
        unsigned p1 = ylb[(size_t)i1 * 32 + lane32];
        unsigned p2 = ylb[(size_t)i2 * 32 + lane32];
        unsigned p3 = ylb[(size_t)i3 * 32 + lane32];
        s0 += bl(p0); s1 += bh(p0);
        t0 += bl(p1); t1 += bh(p1);
        u0 += bl(p2); u1 += bh(p2);
        v0 += bl(p3); v1 += bh(p3);
    }
    for (; k < n2; ++k) {
        int i0 = __shfl(idxB, k, 32);
        unsigned p0 = ylb[(size_t)i0 * 32 + lane32];
        s0 += bl(p0); s1 += bh(p0);
    }

    const float inv = 1.f / fmaxf((float)deg, 1.f);
    const float m0 = ((s0 + t0) + (u0 + v0)) * inv;
    const float m1 = ((s1 + t1) + (u1 + v1)) * inv;

    float2* po = (float2*)&out[(size_t)node * D + lane32 * 2];
    float2 rr = *po;                      // self term written by the pre path
    rr.x = fmaxf(m0 + rr.x, 0.f);
    rr.y = fmaxf(m1 + rr.y, 0.f);
    *po = rr;
}

extern "C" void kernel_launch(void* const* d_in, const int* in_sizes, int n_in,
                              void* d_out, int out_size, void* d_ws, size_t ws_size,
                              hipStream_t stream) {
    const float* x  = (const float*)d_in[0];
    const int*   ei = (const int*)d_in[1];      // [2, E]: row 0 = src, row 1 = dst
    const float* Wl = (const float*)d_in[2];
    const float* Wr = (const float*)d_in[3];
    const float* b  = (const float*)d_in[4];
    float*       out = (float*)d_out;

    const int nN = in_sizes[0] / D;   // 100000
    const int nE = in_sizes[1] / 2;   // 1600000
    const int* src = ei;
    const int* dst = ei + nE;

    // Slot capacity from ws budget: cnt(1) + slots(cap) + ylb(32) words/node.
    // ws >= ~33 MB -> cap ~ 50; P(deg>50) ~ 1e-11 at mean degree 16.
    size_t ws_words = ws_size / 4;
    int cap = (int)min((size_t)64, ws_words / (size_t)nN - 33);

    int* cnt   = (int*)d_ws;                            // [nN]
    int* slots = cnt + nN;                              // [nN*cap]
    unsigned short* ylb = (unsigned short*)(slots + (size_t)nN * cap);  // [nN*64] bf16

    hipMemsetAsync(cnt, 0, (size_t)nN * sizeof(int), stream);

    const int nChunks  = (nE + BK_CHUNK - 1) / BK_CHUNK;   // 391
    const int nScatter = nChunks * 8;                      // 3128
    const int nPre     = (nN + 63) / 64;                   // 1563
    const int nBlocks  = nScatter + nPre;                  // 4691 (2:1 interleave)

    k_fused <<<nBlocks, 256, 0, stream>>>(x, src, dst, Wl, Wr, b, cnt, slots, ylb, out, nE, nN, cap);
    k_gather<<<(nN + 7) / 8, 256, 0, stream>>>((const unsigned int*)ylb, cnt, slots, out, nN, cap);
}